// Round 5
// baseline (319.083 us; speedup 1.0000x reference)
//
#include <hip/hip_runtime.h>

#define N_NODES 100000
#define N_EDGES 1280000
#define DIM 64
#define NBINS 782          // nodes binned by dst>>7 (128 nodes/bin)
#define BINN 128           // nodes per bin
#define CAP 1984           // bin mean 1638, sd 40.5 -> +8.5 sd (validated in R3)
#define EPB 4096           // edges per fill block
#define NFB 313            // ceil(N_EDGES / EPB)
#define CONVB 512          // conv blocks appended after the NBINS sort blocks
#define NTILES 1563        // ceil(N_NODES / 64)
#define FPAD 68            // feat tile leading dim (64+4): keeps b128 align, 2-way banks
#define WSCALE (1.0f / 32767.0f)

typedef float floatx4 __attribute__((ext_vector_type(4)));

__device__ __forceinline__ unsigned bf16_rne(float x) {
    unsigned u = __float_as_uint(x);
    return (u + 0x7fffu + ((u >> 16) & 1u)) >> 16;
}
__device__ __forceinline__ float bf_lo(unsigned q) { return __uint_as_float(q << 16); }
__device__ __forceinline__ float bf_hi(unsigned q) { return __uint_as_float(q & 0xffff0000u); }

// ---- pure fill: bucket edges by dst>>7 into binned[] (R3's fill half, passed) ----
__global__ __launch_bounds__(256) void k_fill(
    const int* __restrict__ src, const float* __restrict__ w,
    const int* __restrict__ dst, int* __restrict__ cursor,
    uint2* __restrict__ binned) {
    __shared__ int h[NBINS];
    __shared__ int base_[NBINS];
    int t = threadIdx.x;
    for (int i = t; i < NBINS; i += 256) h[i] = 0;
    __syncthreads();
    int eb = blockIdx.x * EPB;
    int d[16], sv[16];
    unsigned wq[16];
    #pragma unroll
    for (int j = 0; j < 16; ++j) {
        int e = eb + j * 256 + t;
        if (e < N_EDGES) {
            d[j] = dst[e];
            sv[j] = src[e];
            wq[j] = (unsigned)(w[e] * 32767.0f + 0.5f);
            atomicAdd(&h[d[j] >> 7], 1);
        } else d[j] = -1;
    }
    __syncthreads();
    for (int i = t; i < NBINS; i += 256) {
        int c = h[i];
        base_[i] = c ? atomicAdd(&cursor[i], c) : 0;
        h[i] = 0;   // reuse as local cursor
    }
    __syncthreads();
    #pragma unroll
    for (int j = 0; j < 16; ++j) {
        if (d[j] >= 0) {
            int bin = d[j] >> 7;
            int pos = base_[bin] + atomicAdd(&h[bin], 1);
            binned[bin * CAP + pos] =
                make_uint2((unsigned)sv[j] | ((unsigned)(d[j] & 127) << 17), wq[j]);
        }
    }
}

// ---- fused: blocks [0,NBINS) per-bin counting sort -> packed CSR; blocks
// [NBINS,NBINS+CONVB) compute fW=bf16(feat@W). Conv overlaps the sort phase
// (it has no deps on fill output), shortening the critical path.
__global__ __launch_bounds__(512) void k_sortconv(
    const uint2* __restrict__ binned, const int* __restrict__ cursor,
    unsigned* __restrict__ csrp, int2* __restrict__ noff,
    const float* __restrict__ feat, const float* __restrict__ W,
    unsigned short* __restrict__ fW) {
    __shared__ union U {
        struct { int h[BINN]; int excl[BINN]; unsigned stage[CAP]; } so;
        struct { float w[DIM * DIM]; float f[64 * FPAD]; } conv;
        __device__ U() {}
    } sm;
    int t = threadIdx.x;

    if (blockIdx.x < NBINS) {
        // ---------------- sort half ----------------
        int b = blockIdx.x;
        int total = cursor[b];
        int segbase = b * CAP;
        if (t < BINN) sm.so.h[t] = 0;
        __syncthreads();
        for (int i = t; i < total; i += 512)
            atomicAdd(&sm.so.h[(binned[segbase + i].x >> 17) & 127], 1);
        __syncthreads();
        int v = 0;
        if (t < BINN) { v = sm.so.h[t]; sm.so.excl[t] = v; }
        __syncthreads();
        for (int off = 1; off < BINN; off <<= 1) {
            int add = 0;
            if (t < BINN && t >= off) add = sm.so.excl[t - off];
            __syncthreads();
            if (t < BINN) sm.so.excl[t] += add;
            __syncthreads();
        }
        if (t < BINN) {
            int ex = sm.so.excl[t] - v;
            sm.so.excl[t] = ex;
            int node = (b << 7) + t;
            if (node < N_NODES) noff[node] = make_int2(segbase + ex, v);
            sm.so.h[t] = 0;   // reuse as per-node cursor
        }
        __syncthreads();
        for (int i = t; i < total; i += 512) {
            uint2 e = binned[segbase + i];
            int o = (e.x >> 17) & 127;
            int pos = sm.so.excl[o] + atomicAdd(&sm.so.h[o], 1);
            if (pos < CAP) sm.so.stage[pos] = (e.x & 0x1ffffu) | (e.y << 17);
        }
        __syncthreads();
        for (int i = t; i < total; i += 512)
            csrp[segbase + i] = sm.so.stage[i];   // coalesced flush
    } else {
        // ---------------- conv half: fW = bf16(feat @ W), 512-thread layout ----
        #pragma unroll
        for (int i = 0; i < DIM * DIM / 512; ++i)
            sm.conv.w[t + i * 512] = W[t + i * 512];
        const float4* lds_w4 = (const float4*)sm.conv.w;
        float4* lds_f4 = (float4*)sm.conv.f;
        int tx = t & 15, ny = t >> 4;       // thread tile: nodes ny*2..+1, outs tx*4..+3
        int rr = t >> 3, seg = t & 7;       // staging: row rr, 2-float4 segment seg

        for (int tb = blockIdx.x - NBINS; tb < NTILES; tb += CONVB) {
            int nb = tb * 64;
            __syncthreads();   // protect lds_f from previous tile's readers (fences W stage)
            #pragma unroll
            for (int q = 0; q < 2; ++q) {
                float4 v = (nb + rr < N_NODES)
                           ? ((const float4*)feat)[(size_t)(nb + rr) * 16 + seg * 2 + q]
                           : make_float4(0.f, 0.f, 0.f, 0.f);
                lds_f4[(rr * FPAD + seg * 8 + q * 4) >> 2] = v;
            }
            __syncthreads();
            float acc[2][4];
            #pragma unroll
            for (int i = 0; i < 2; ++i)
                #pragma unroll
                for (int j = 0; j < 4; ++j) acc[i][j] = 0.f;
            for (int k0 = 0; k0 < DIM; k0 += 4) {
                float4 hv[2], wv[4];
                #pragma unroll
                for (int i = 0; i < 2; ++i)
                    hv[i] = lds_f4[((ny * 2 + i) * FPAD + k0) >> 2];
                #pragma unroll
                for (int j = 0; j < 4; ++j)
                    wv[j] = lds_w4[((k0 + j) * DIM + tx * 4) >> 2];
                #pragma unroll
                for (int i = 0; i < 2; ++i) {
                    const float* hp = (const float*)&hv[i];
                    #pragma unroll
                    for (int kk = 0; kk < 4; ++kk) {
                        float hk = hp[kk];
                        acc[i][0] = fmaf(hk, ((const float*)&wv[kk])[0], acc[i][0]);
                        acc[i][1] = fmaf(hk, ((const float*)&wv[kk])[1], acc[i][1]);
                        acc[i][2] = fmaf(hk, ((const float*)&wv[kk])[2], acc[i][2]);
                        acc[i][3] = fmaf(hk, ((const float*)&wv[kk])[3], acc[i][3]);
                    }
                }
            }
            #pragma unroll
            for (int i = 0; i < 2; ++i) {
                int node = nb + ny * 2 + i;
                if (node < N_NODES) {
                    ushort4 o;
                    o.x = (unsigned short)bf16_rne(acc[i][0]);
                    o.y = (unsigned short)bf16_rne(acc[i][1]);
                    o.z = (unsigned short)bf16_rne(acc[i][2]);
                    o.w = (unsigned short)bf16_rne(acc[i][3]);
                    *(ushort4*)(fW + (size_t)node * DIM + tx * 4) = o;
                }
            }
        }
    }
}

// ---- gather fW rows per node, normalize, store (unchanged from R4 — won) ----
// TWO nodes per wave: half h = lane>>5; 4 groups x 8 lanes, 16 slots/round.
__global__ __launch_bounds__(256) void k_gather(const uint4* __restrict__ fW4,
                                                const unsigned* __restrict__ csrp,
                                                const int2* __restrict__ noff,
                                                float* __restrict__ out) {
    int lane = threadIdx.x & 63;
    int h = lane >> 5;           // node within pair
    int g2 = (lane >> 3) & 3;    // chain group
    int s = lane & 7;            // dim segment
    int wave = (blockIdx.x * 256 + threadIdx.x) >> 6;
    int nw = gridDim.x * 4;

    for (int pair = wave; pair < N_NODES / 2; pair += nw) {
        int node = pair * 2 + h;
        int2 oc = noff[node];
        int start = oc.x, c = oc.y;
        int end = start + c;
        float a[8] = {0, 0, 0, 0, 0, 0, 0, 0};
        for (int i = start; i < end; i += 16) {
            int i0 = i + g2, i1 = i + 4 + g2, i2 = i + 8 + g2, i3 = i + 12 + g2;
            unsigned p0 = __builtin_nontemporal_load(csrp + ((i0 < end) ? i0 : start));
            unsigned p1 = __builtin_nontemporal_load(csrp + ((i1 < end) ? i1 : start));
            unsigned p2 = __builtin_nontemporal_load(csrp + ((i2 < end) ? i2 : start));
            unsigned p3 = __builtin_nontemporal_load(csrp + ((i3 < end) ? i3 : start));
            float w0 = (i0 < end) ? (float)(p0 >> 17) * WSCALE : 0.f;
            float w1 = (i1 < end) ? (float)(p1 >> 17) * WSCALE : 0.f;
            float w2 = (i2 < end) ? (float)(p2 >> 17) * WSCALE : 0.f;
            float w3 = (i3 < end) ? (float)(p3 >> 17) * WSCALE : 0.f;
            uint4 q0 = fW4[((size_t)(p0 & 0x1ffffu) << 3) + s];
            uint4 q1 = fW4[((size_t)(p1 & 0x1ffffu) << 3) + s];
            uint4 q2 = fW4[((size_t)(p2 & 0x1ffffu) << 3) + s];
            uint4 q3 = fW4[((size_t)(p3 & 0x1ffffu) << 3) + s];
            a[0] = fmaf(bf_lo(q0.x), w0, a[0]); a[1] = fmaf(bf_hi(q0.x), w0, a[1]);
            a[2] = fmaf(bf_lo(q0.y), w0, a[2]); a[3] = fmaf(bf_hi(q0.y), w0, a[3]);
            a[4] = fmaf(bf_lo(q0.z), w0, a[4]); a[5] = fmaf(bf_hi(q0.z), w0, a[5]);
            a[6] = fmaf(bf_lo(q0.w), w0, a[6]); a[7] = fmaf(bf_hi(q0.w), w0, a[7]);
            a[0] = fmaf(bf_lo(q1.x), w1, a[0]); a[1] = fmaf(bf_hi(q1.x), w1, a[1]);
            a[2] = fmaf(bf_lo(q1.y), w1, a[2]); a[3] = fmaf(bf_hi(q1.y), w1, a[3]);
            a[4] = fmaf(bf_lo(q1.z), w1, a[4]); a[5] = fmaf(bf_hi(q1.z), w1, a[5]);
            a[6] = fmaf(bf_lo(q1.w), w1, a[6]); a[7] = fmaf(bf_hi(q1.w), w1, a[7]);
            a[0] = fmaf(bf_lo(q2.x), w2, a[0]); a[1] = fmaf(bf_hi(q2.x), w2, a[1]);
            a[2] = fmaf(bf_lo(q2.y), w2, a[2]); a[3] = fmaf(bf_hi(q2.y), w2, a[3]);
            a[4] = fmaf(bf_lo(q2.z), w2, a[4]); a[5] = fmaf(bf_hi(q2.z), w2, a[5]);
            a[6] = fmaf(bf_lo(q2.w), w2, a[6]); a[7] = fmaf(bf_hi(q2.w), w2, a[7]);
            a[0] = fmaf(bf_lo(q3.x), w3, a[0]); a[1] = fmaf(bf_hi(q3.x), w3, a[1]);
            a[2] = fmaf(bf_lo(q3.y), w3, a[2]); a[3] = fmaf(bf_hi(q3.y), w3, a[3]);
            a[4] = fmaf(bf_lo(q3.z), w3, a[4]); a[5] = fmaf(bf_hi(q3.z), w3, a[5]);
            a[6] = fmaf(bf_lo(q3.w), w3, a[6]); a[7] = fmaf(bf_hi(q3.w), w3, a[7]);
        }
        #pragma unroll
        for (int j = 0; j < 8; ++j) {     // reduce over the 4 groups of this half
            a[j] += __shfl_xor(a[j], 8, 64);
            a[j] += __shfl_xor(a[j], 16, 64);
        }
        float dinv = 1.0f / fmaxf((float)c, 1.0f);
        if (g2 == 0) {   // lanes 0..7 (half 0) and 32..39 (half 1)
            floatx4 o0, o1;
            o0.x = a[0] * dinv; o0.y = a[1] * dinv; o0.z = a[2] * dinv; o0.w = a[3] * dinv;
            o1.x = a[4] * dinv; o1.y = a[5] * dinv; o1.z = a[6] * dinv; o1.w = a[7] * dinv;
            floatx4* op = (floatx4*)out + (size_t)node * 16 + s * 2;
            __builtin_nontemporal_store(o0, op + 0);
            __builtin_nontemporal_store(o1, op + 1);
        }
    }
}

extern "C" void kernel_launch(void* const* d_in, const int* in_sizes, int n_in,
                              void* d_out, int out_size, void* d_ws, size_t ws_size,
                              hipStream_t stream) {
    const float* feat = (const float*)d_in[0];
    const float* w    = (const float*)d_in[1];
    const float* W    = (const float*)d_in[2];
    const int*   src  = (const int*)d_in[3];
    const int*   dst  = (const int*)d_in[4];
    float* out = (float*)d_out;

    // fW 12.8 MB + binned 12.4 MB + csrp 6.2 MB + noff + cursor; ws is 256 MiB.
    unsigned short* fW = (unsigned short*)d_ws;                  // 16B-aligned
    uint2* binned  = (uint2*)(fW + (size_t)N_NODES * DIM);
    unsigned* csrp = (unsigned*)(binned + (size_t)NBINS * CAP);
    int2* noff     = (int2*)(csrp + (size_t)NBINS * CAP);
    int* cursor    = (int*)(noff + N_NODES);

    hipMemsetAsync(cursor, 0, NBINS * sizeof(int), stream);

    k_fill<<<NFB, 256, 0, stream>>>(src, w, dst, cursor, binned);
    k_sortconv<<<NBINS + CONVB, 512, 0, stream>>>(binned, cursor, csrp, noff,
                                                  feat, W, fW);
    k_gather<<<4096, 256, 0, stream>>>((const uint4*)fW, csrp, noff, out);
}

// Round 6
// 144.774 us; speedup vs baseline: 2.2040x; 2.2040x over previous
//
#include <hip/hip_runtime.h>

#define N_NODES 100000
#define N_EDGES 1280000
#define DIM 64
#define NBINS 782          // nodes binned by dst>>7 (128 nodes/bin)
#define BINN 128           // nodes per bin
#define CAP 1984           // bin mean 1638, sd 40.5 -> +8.5 sd (validated R3)
#define EPB 4096           // edges per fill block
#define NFB 313            // ceil(N_EDGES / EPB)
#define CONVB 512          // conv blocks appended after the NFB fill blocks
#define NTILES 1563        // ceil(N_NODES / 64)
#define FPAD 68            // feat tile leading dim (64+4): keeps b128 align, 2-way banks
#define WSCALE (1.0f / 32767.0f)

typedef float floatx4 __attribute__((ext_vector_type(4)));

__device__ __forceinline__ unsigned bf16_rne(float x) {
    unsigned u = __float_as_uint(x);
    return (u + 0x7fffu + ((u >> 16) & 1u)) >> 16;
}
__device__ __forceinline__ float bf_lo(unsigned q) { return __uint_as_float(q << 16); }
__device__ __forceinline__ float bf_hi(unsigned q) { return __uint_as_float(q & 0xffff0000u); }

// ---- fused: blocks [0,NFB) bucket edges by dst>>7; blocks [NFB,NFB+CONVB) compute
// fW=bf16(feat@W). Structure identical to R4's (142.9 us pipeline); only the
// binning granularity changed (R3-verified fill half).
__global__ __launch_bounds__(256) void k_fill_conv(
    const int* __restrict__ src, const float* __restrict__ w,
    const int* __restrict__ dst, int* __restrict__ cursor,
    uint2* __restrict__ binned,
    const float* __restrict__ feat, const float* __restrict__ W,
    unsigned short* __restrict__ fW) {
    __shared__ union U {
        struct { int h[NBINS]; int base_[NBINS]; } fill;
        struct { float w[DIM * DIM]; float f[64 * FPAD]; } conv;
        __device__ U() {}
    } sm;
    int t = threadIdx.x;

    if (blockIdx.x < NFB) {
        // ---------------- fill half ----------------
        for (int i = t; i < NBINS; i += 256) sm.fill.h[i] = 0;
        __syncthreads();
        int eb = blockIdx.x * EPB;
        int d[16], sv[16];
        unsigned wq[16];
        #pragma unroll
        for (int j = 0; j < 16; ++j) {
            int e = eb + j * 256 + t;
            if (e < N_EDGES) {
                d[j] = dst[e];
                sv[j] = src[e];
                wq[j] = (unsigned)(w[e] * 32767.0f + 0.5f);
                atomicAdd(&sm.fill.h[d[j] >> 7], 1);
            } else d[j] = -1;
        }
        __syncthreads();
        for (int i = t; i < NBINS; i += 256) {
            int c = sm.fill.h[i];
            sm.fill.base_[i] = c ? atomicAdd(&cursor[i], c) : 0;
            sm.fill.h[i] = 0;   // reuse as local cursor
        }
        __syncthreads();
        #pragma unroll
        for (int j = 0; j < 16; ++j) {
            if (d[j] >= 0) {
                int bin = d[j] >> 7;
                int pos = sm.fill.base_[bin] + atomicAdd(&sm.fill.h[bin], 1);
                binned[bin * CAP + pos] =
                    make_uint2((unsigned)sv[j] | ((unsigned)(d[j] & 127) << 17), wq[j]);
            }
        }
    } else {
        // ---------------- conv half: fW = bf16(feat @ W), LDS-tiled ----------------
        #pragma unroll
        for (int i = 0; i < DIM * DIM / 256; ++i)
            sm.conv.w[t + i * 256] = W[t + i * 256];
        const float4* lds_w4 = (const float4*)sm.conv.w;
        float4* lds_f4 = (float4*)sm.conv.f;
        int tx = t & 15, ny = t >> 4;       // thread tile: nodes ny*4..+3, outs tx*4..+3
        int rr = t >> 2, seg = t & 3;       // staging: row rr, 16-float segment seg

        for (int tb = blockIdx.x - NFB; tb < NTILES; tb += CONVB) {
            int nb = tb * 64;
            __syncthreads();   // protect lds_f from previous tile's readers (also fences W stage)
            #pragma unroll
            for (int q = 0; q < 4; ++q) {
                float4 v = (nb + rr < N_NODES)
                           ? ((const float4*)feat)[(size_t)(nb + rr) * 16 + seg * 4 + q]
                           : make_float4(0.f, 0.f, 0.f, 0.f);
                lds_f4[(rr * FPAD + seg * 16 + q * 4) >> 2] = v;
            }
            __syncthreads();
            float acc[4][4];
            #pragma unroll
            for (int i = 0; i < 4; ++i)
                #pragma unroll
                for (int j = 0; j < 4; ++j) acc[i][j] = 0.f;
            for (int k0 = 0; k0 < DIM; k0 += 4) {
                float4 hv[4], wv[4];
                #pragma unroll
                for (int i = 0; i < 4; ++i)
                    hv[i] = lds_f4[((ny * 4 + i) * FPAD + k0) >> 2];
                #pragma unroll
                for (int j = 0; j < 4; ++j)
                    wv[j] = lds_w4[((k0 + j) * DIM + tx * 4) >> 2];
                #pragma unroll
                for (int i = 0; i < 4; ++i) {
                    const float* hp = (const float*)&hv[i];
                    #pragma unroll
                    for (int kk = 0; kk < 4; ++kk) {
                        float hk = hp[kk];
                        acc[i][0] = fmaf(hk, ((const float*)&wv[kk])[0], acc[i][0]);
                        acc[i][1] = fmaf(hk, ((const float*)&wv[kk])[1], acc[i][1]);
                        acc[i][2] = fmaf(hk, ((const float*)&wv[kk])[2], acc[i][2]);
                        acc[i][3] = fmaf(hk, ((const float*)&wv[kk])[3], acc[i][3]);
                    }
                }
            }
            #pragma unroll
            for (int i = 0; i < 4; ++i) {
                int node = nb + ny * 4 + i;
                if (node < N_NODES) {
                    ushort4 o;
                    o.x = (unsigned short)bf16_rne(acc[i][0]);
                    o.y = (unsigned short)bf16_rne(acc[i][1]);
                    o.z = (unsigned short)bf16_rne(acc[i][2]);
                    o.w = (unsigned short)bf16_rne(acc[i][3]);
                    *(ushort4*)(fW + (size_t)node * DIM + tx * 4) = o;
                }
            }
        }
    }
}

// ---- per-bin in-LDS counting sort -> packed CSR (src17|w15), int2{offs,cnt} ----
// 782 blocks (~3/CU, one resident round), 9 KB LDS, edges register-staged in
// 4 named scalars (no dynamic-index array -> no scratch), binned read ONCE.
__global__ __launch_bounds__(512) void k_sortbin(const uint2* __restrict__ binned,
                                                 const int* __restrict__ cursor,
                                                 unsigned* __restrict__ csrp,
                                                 int2* __restrict__ noff) {
    __shared__ int h[BINN];
    __shared__ int excl[BINN];
    __shared__ unsigned stage[CAP];
    int b = blockIdx.x, t = threadIdx.x;
    int total = cursor[b];
    int segbase = b * CAP;
    if (t < BINN) h[t] = 0;
    __syncthreads();

    // load (<=4 edges/thread, CAP=1984 <= 4*512) + histogram
    int i0 = t, i1 = t + 512, i2 = t + 1024, i3 = t + 1536;
    uint2 e0 = make_uint2(0, 0), e1 = e0, e2 = e0, e3 = e0;
    if (i0 < total) { e0 = binned[segbase + i0]; atomicAdd(&h[(e0.x >> 17) & 127], 1); }
    if (i1 < total) { e1 = binned[segbase + i1]; atomicAdd(&h[(e1.x >> 17) & 127], 1); }
    if (i2 < total) { e2 = binned[segbase + i2]; atomicAdd(&h[(e2.x >> 17) & 127], 1); }
    if (i3 < total) { e3 = binned[segbase + i3]; atomicAdd(&h[(e3.x >> 17) & 127], 1); }
    __syncthreads();

    // exclusive scan over 128 counts
    int v = 0;
    if (t < BINN) { v = h[t]; excl[t] = v; }
    __syncthreads();
    for (int off = 1; off < BINN; off <<= 1) {
        int add = 0;
        if (t < BINN && t >= off) add = excl[t - off];
        __syncthreads();
        if (t < BINN) excl[t] += add;
        __syncthreads();
    }
    if (t < BINN) {
        int ex = excl[t] - v;
        excl[t] = ex;
        int node = (b << 7) + t;
        if (node < N_NODES) noff[node] = make_int2(segbase + ex, v);
        h[t] = 0;   // reuse as per-node cursor
    }
    __syncthreads();

    // scatter from registers into node-sorted stage
    if (i0 < total) { int o = (e0.x >> 17) & 127; int p = excl[o] + atomicAdd(&h[o], 1);
                      stage[p] = (e0.x & 0x1ffffu) | (e0.y << 17); }
    if (i1 < total) { int o = (e1.x >> 17) & 127; int p = excl[o] + atomicAdd(&h[o], 1);
                      stage[p] = (e1.x & 0x1ffffu) | (e1.y << 17); }
    if (i2 < total) { int o = (e2.x >> 17) & 127; int p = excl[o] + atomicAdd(&h[o], 1);
                      stage[p] = (e2.x & 0x1ffffu) | (e2.y << 17); }
    if (i3 < total) { int o = (e3.x >> 17) & 127; int p = excl[o] + atomicAdd(&h[o], 1);
                      stage[p] = (e3.x & 0x1ffffu) | (e3.y << 17); }
    __syncthreads();

    for (int i = t; i < total; i += 512)
        csrp[segbase + i] = stage[i];   // coalesced flush
}

// ---- gather fW rows per node, normalize, store (unchanged from R4 — won) ----
// TWO nodes per wave: half h = lane>>5; 4 groups x 8 lanes, 16 slots/round.
__global__ __launch_bounds__(256) void k_gather(const uint4* __restrict__ fW4,
                                                const unsigned* __restrict__ csrp,
                                                const int2* __restrict__ noff,
                                                float* __restrict__ out) {
    int lane = threadIdx.x & 63;
    int h = lane >> 5;           // node within pair
    int g2 = (lane >> 3) & 3;    // chain group
    int s = lane & 7;            // dim segment
    int wave = (blockIdx.x * 256 + threadIdx.x) >> 6;
    int nw = gridDim.x * 4;

    for (int pair = wave; pair < N_NODES / 2; pair += nw) {
        int node = pair * 2 + h;
        int2 oc = noff[node];
        int start = oc.x, c = oc.y;
        int end = start + c;
        float a[8] = {0, 0, 0, 0, 0, 0, 0, 0};
        for (int i = start; i < end; i += 16) {
            int i0 = i + g2, i1 = i + 4 + g2, i2 = i + 8 + g2, i3 = i + 12 + g2;
            unsigned p0 = __builtin_nontemporal_load(csrp + ((i0 < end) ? i0 : start));
            unsigned p1 = __builtin_nontemporal_load(csrp + ((i1 < end) ? i1 : start));
            unsigned p2 = __builtin_nontemporal_load(csrp + ((i2 < end) ? i2 : start));
            unsigned p3 = __builtin_nontemporal_load(csrp + ((i3 < end) ? i3 : start));
            float w0 = (i0 < end) ? (float)(p0 >> 17) * WSCALE : 0.f;
            float w1 = (i1 < end) ? (float)(p1 >> 17) * WSCALE : 0.f;
            float w2 = (i2 < end) ? (float)(p2 >> 17) * WSCALE : 0.f;
            float w3 = (i3 < end) ? (float)(p3 >> 17) * WSCALE : 0.f;
            uint4 q0 = fW4[((size_t)(p0 & 0x1ffffu) << 3) + s];
            uint4 q1 = fW4[((size_t)(p1 & 0x1ffffu) << 3) + s];
            uint4 q2 = fW4[((size_t)(p2 & 0x1ffffu) << 3) + s];
            uint4 q3 = fW4[((size_t)(p3 & 0x1ffffu) << 3) + s];
            a[0] = fmaf(bf_lo(q0.x), w0, a[0]); a[1] = fmaf(bf_hi(q0.x), w0, a[1]);
            a[2] = fmaf(bf_lo(q0.y), w0, a[2]); a[3] = fmaf(bf_hi(q0.y), w0, a[3]);
            a[4] = fmaf(bf_lo(q0.z), w0, a[4]); a[5] = fmaf(bf_hi(q0.z), w0, a[5]);
            a[6] = fmaf(bf_lo(q0.w), w0, a[6]); a[7] = fmaf(bf_hi(q0.w), w0, a[7]);
            a[0] = fmaf(bf_lo(q1.x), w1, a[0]); a[1] = fmaf(bf_hi(q1.x), w1, a[1]);
            a[2] = fmaf(bf_lo(q1.y), w1, a[2]); a[3] = fmaf(bf_hi(q1.y), w1, a[3]);
            a[4] = fmaf(bf_lo(q1.z), w1, a[4]); a[5] = fmaf(bf_hi(q1.z), w1, a[5]);
            a[6] = fmaf(bf_lo(q1.w), w1, a[6]); a[7] = fmaf(bf_hi(q1.w), w1, a[7]);
            a[0] = fmaf(bf_lo(q2.x), w2, a[0]); a[1] = fmaf(bf_hi(q2.x), w2, a[1]);
            a[2] = fmaf(bf_lo(q2.y), w2, a[2]); a[3] = fmaf(bf_hi(q2.y), w2, a[3]);
            a[4] = fmaf(bf_lo(q2.z), w2, a[4]); a[5] = fmaf(bf_hi(q2.z), w2, a[5]);
            a[6] = fmaf(bf_lo(q2.w), w2, a[6]); a[7] = fmaf(bf_hi(q2.w), w2, a[7]);
            a[0] = fmaf(bf_lo(q3.x), w3, a[0]); a[1] = fmaf(bf_hi(q3.x), w3, a[1]);
            a[2] = fmaf(bf_lo(q3.y), w3, a[2]); a[3] = fmaf(bf_hi(q3.y), w3, a[3]);
            a[4] = fmaf(bf_lo(q3.z), w3, a[4]); a[5] = fmaf(bf_hi(q3.z), w3, a[5]);
            a[6] = fmaf(bf_lo(q3.w), w3, a[6]); a[7] = fmaf(bf_hi(q3.w), w3, a[7]);
        }
        #pragma unroll
        for (int j = 0; j < 8; ++j) {     // reduce over the 4 groups of this half
            a[j] += __shfl_xor(a[j], 8, 64);
            a[j] += __shfl_xor(a[j], 16, 64);
        }
        float dinv = 1.0f / fmaxf((float)c, 1.0f);
        if (g2 == 0) {   // lanes 0..7 (half 0) and 32..39 (half 1)
            floatx4 o0, o1;
            o0.x = a[0] * dinv; o0.y = a[1] * dinv; o0.z = a[2] * dinv; o0.w = a[3] * dinv;
            o1.x = a[4] * dinv; o1.y = a[5] * dinv; o1.z = a[6] * dinv; o1.w = a[7] * dinv;
            floatx4* op = (floatx4*)out + (size_t)node * 16 + s * 2;
            __builtin_nontemporal_store(o0, op + 0);
            __builtin_nontemporal_store(o1, op + 1);
        }
    }
}

extern "C" void kernel_launch(void* const* d_in, const int* in_sizes, int n_in,
                              void* d_out, int out_size, void* d_ws, size_t ws_size,
                              hipStream_t stream) {
    const float* feat = (const float*)d_in[0];
    const float* w    = (const float*)d_in[1];
    const float* W    = (const float*)d_in[2];
    const int*   src  = (const int*)d_in[3];
    const int*   dst  = (const int*)d_in[4];
    float* out = (float*)d_out;

    // fW 12.8 MB + binned 12.4 MB + csrp 6.2 MB + noff + cursor; ws is 256 MiB.
    unsigned short* fW = (unsigned short*)d_ws;                  // 16B-aligned
    uint2* binned  = (uint2*)(fW + (size_t)N_NODES * DIM);
    unsigned* csrp = (unsigned*)(binned + (size_t)NBINS * CAP);
    int2* noff     = (int2*)(csrp + (size_t)NBINS * CAP);
    int* cursor    = (int*)(noff + N_NODES);

    hipMemsetAsync(cursor, 0, NBINS * sizeof(int), stream);

    k_fill_conv<<<NFB + CONVB, 256, 0, stream>>>(src, w, dst, cursor, binned,
                                                 feat, W, fW);
    k_sortbin<<<NBINS, 512, 0, stream>>>(binned, cursor, csrp, noff);
    k_gather<<<4096, 256, 0, stream>>>((const uint4*)fW, csrp, noff, out);
}

// Round 8
// 141.005 us; speedup vs baseline: 2.2629x; 1.0267x over previous
//
#include <hip/hip_runtime.h>

#define N_NODES 100000
#define N_EDGES 1280000
#define DIM 64
#define NBINS 391          // nodes binned by dst>>8 (256 nodes/bin)
#define CAP 3712           // bin mean 3274, sd 57 -> +7.6 sd
#define EPB 4096           // edges per fill block
#define NFB 313            // ceil(N_EDGES / EPB)
#define CONVB 512          // conv blocks appended after the NFB fill blocks
#define NTILES 1563        // ceil(N_NODES / 64)
#define FPAD 68            // feat tile leading dim (64+4): keeps b128 align, 2-way banks
#define WSCALE (1.0f / 32767.0f)

typedef float floatx4 __attribute__((ext_vector_type(4)));

__device__ __forceinline__ unsigned bf16_rne(float x) {
    unsigned u = __float_as_uint(x);
    return (u + 0x7fffu + ((u >> 16) & 1u)) >> 16;
}
__device__ __forceinline__ float bf_lo(unsigned q) { return __uint_as_float(q << 16); }
__device__ __forceinline__ float bf_hi(unsigned q) { return __uint_as_float(q & 0xffff0000u); }

// ---- fused: blocks [0,NFB) bucket edges; blocks [NFB,NFB+CONVB) compute fW=bf16(feat@W)
// (exact R4 version — measured in the 142.9 us pipeline)
__global__ __launch_bounds__(256) void k_fill_conv(
    const int* __restrict__ src, const float* __restrict__ w,
    const int* __restrict__ dst, int* __restrict__ cursor,
    uint2* __restrict__ binned,
    const float* __restrict__ feat, const float* __restrict__ W,
    unsigned short* __restrict__ fW) {
    __shared__ union U {
        struct { int h[NBINS]; int base_[NBINS]; } fill;
        struct { float w[DIM * DIM]; float f[64 * FPAD]; } conv;
        __device__ U() {}
    } sm;
    int t = threadIdx.x;

    if (blockIdx.x < NFB) {
        // ---------------- fill half ----------------
        for (int i = t; i < NBINS; i += 256) sm.fill.h[i] = 0;
        __syncthreads();
        int eb = blockIdx.x * EPB;
        int d[16], sv[16];
        unsigned wq[16];
        #pragma unroll
        for (int j = 0; j < 16; ++j) {
            int e = eb + j * 256 + t;
            if (e < N_EDGES) {
                d[j] = dst[e];
                sv[j] = src[e];
                wq[j] = (unsigned)(w[e] * 32767.0f + 0.5f);
                atomicAdd(&sm.fill.h[d[j] >> 8], 1);
            } else d[j] = -1;
        }
        __syncthreads();
        for (int i = t; i < NBINS; i += 256) {
            int c = sm.fill.h[i];
            sm.fill.base_[i] = c ? atomicAdd(&cursor[i], c) : 0;
            sm.fill.h[i] = 0;   // reuse as local cursor
        }
        __syncthreads();
        #pragma unroll
        for (int j = 0; j < 16; ++j) {
            if (d[j] >= 0) {
                int bin = d[j] >> 8;
                int pos = sm.fill.base_[bin] + atomicAdd(&sm.fill.h[bin], 1);
                binned[bin * CAP + pos] =
                    make_uint2((unsigned)sv[j] | ((unsigned)(d[j] & 255) << 17), wq[j]);
            }
        }
    } else {
        // ---------------- conv half: fW = bf16(feat @ W), LDS-tiled ----------------
        #pragma unroll
        for (int i = 0; i < DIM * DIM / 256; ++i)
            sm.conv.w[t + i * 256] = W[t + i * 256];
        const float4* lds_w4 = (const float4*)sm.conv.w;
        float4* lds_f4 = (float4*)sm.conv.f;
        int tx = t & 15, ny = t >> 4;       // thread tile: nodes ny*4..+3, outs tx*4..+3
        int rr = t >> 2, seg = t & 3;       // staging: row rr, 16-float segment seg

        for (int tb = blockIdx.x - NFB; tb < NTILES; tb += CONVB) {
            int nb = tb * 64;
            __syncthreads();   // protect lds_f from previous tile's readers (also fences W stage)
            #pragma unroll
            for (int q = 0; q < 4; ++q) {
                float4 v = (nb + rr < N_NODES)
                           ? ((const float4*)feat)[(size_t)(nb + rr) * 16 + seg * 4 + q]
                           : make_float4(0.f, 0.f, 0.f, 0.f);
                lds_f4[(rr * FPAD + seg * 16 + q * 4) >> 2] = v;
            }
            __syncthreads();
            float acc[4][4];
            #pragma unroll
            for (int i = 0; i < 4; ++i)
                #pragma unroll
                for (int j = 0; j < 4; ++j) acc[i][j] = 0.f;
            for (int k0 = 0; k0 < DIM; k0 += 4) {
                float4 hv[4], wv[4];
                #pragma unroll
                for (int i = 0; i < 4; ++i)
                    hv[i] = lds_f4[((ny * 4 + i) * FPAD + k0) >> 2];
                #pragma unroll
                for (int j = 0; j < 4; ++j)
                    wv[j] = lds_w4[((k0 + j) * DIM + tx * 4) >> 2];
                #pragma unroll
                for (int i = 0; i < 4; ++i) {
                    const float* hp = (const float*)&hv[i];
                    #pragma unroll
                    for (int kk = 0; kk < 4; ++kk) {
                        float hk = hp[kk];
                        acc[i][0] = fmaf(hk, ((const float*)&wv[kk])[0], acc[i][0]);
                        acc[i][1] = fmaf(hk, ((const float*)&wv[kk])[1], acc[i][1]);
                        acc[i][2] = fmaf(hk, ((const float*)&wv[kk])[2], acc[i][2]);
                        acc[i][3] = fmaf(hk, ((const float*)&wv[kk])[3], acc[i][3]);
                    }
                }
            }
            #pragma unroll
            for (int i = 0; i < 4; ++i) {
                int node = nb + ny * 4 + i;
                if (node < N_NODES) {
                    ushort4 o;
                    o.x = (unsigned short)bf16_rne(acc[i][0]);
                    o.y = (unsigned short)bf16_rne(acc[i][1]);
                    o.z = (unsigned short)bf16_rne(acc[i][2]);
                    o.w = (unsigned short)bf16_rne(acc[i][3]);
                    *(ushort4*)(fW + (size_t)node * DIM + tx * 4) = o;
                }
            }
        }
    }
}

// ---- per-bin in-LDS counting sort -> packed CSR (src17|w15), int2{offs,cnt} ----
// (exact R4 version)
__global__ __launch_bounds__(512) void k_sortbin(const uint2* __restrict__ binned,
                                                 const int* __restrict__ cursor,
                                                 unsigned* __restrict__ csrp,
                                                 int2* __restrict__ noff) {
    __shared__ int h[256];
    __shared__ int excl[256];
    __shared__ unsigned stage[CAP];
    int b = blockIdx.x, t = threadIdx.x;
    int total = cursor[b];
    int segbase = b * CAP;
    if (t < 256) h[t] = 0;
    __syncthreads();
    for (int i = t; i < total; i += 512)
        atomicAdd(&h[(binned[segbase + i].x >> 17) & 255], 1);
    __syncthreads();
    int v = 0;
    if (t < 256) { v = h[t]; excl[t] = v; }
    __syncthreads();
    for (int off = 1; off < 256; off <<= 1) {
        int add = 0;
        if (t < 256 && t >= off) add = excl[t - off];
        __syncthreads();
        if (t < 256) excl[t] += add;
        __syncthreads();
    }
    if (t < 256) {
        int ex = excl[t] - v;
        excl[t] = ex;
        int node = (b << 8) + t;
        if (node < N_NODES) noff[node] = make_int2(segbase + ex, v);
        h[t] = 0;   // reuse as per-node cursor
    }
    __syncthreads();
    for (int i = t; i < total; i += 512) {
        uint2 e = binned[segbase + i];
        int o = (e.x >> 17) & 255;
        int pos = excl[o] + atomicAdd(&h[o], 1);
        if (pos < CAP) stage[pos] = (e.x & 0x1ffffu) | (e.y << 17);
    }
    __syncthreads();
    for (int i = t; i < total; i += 512)
        csrp[segbase + i] = stage[i];   // coalesced flush
}

// ---- gather fW rows per node, normalize, store ----
// R4 structure (2 nodes/wave, 16 slots/round) with three isolated changes:
// (1) csrp loads are PLAIN (nt bypassed L2 on freshly-written data),
// (2) next pair's noff prefetched across the loop body,
// (3) grid 6144 for extra TLP.
__global__ __launch_bounds__(256) void k_gather(const uint4* __restrict__ fW4,
                                                const unsigned* __restrict__ csrp,
                                                const int2* __restrict__ noff,
                                                float* __restrict__ out) {
    int lane = threadIdx.x & 63;
    int h = lane >> 5;           // node within pair
    int g2 = (lane >> 3) & 3;    // chain group
    int s = lane & 7;            // dim segment
    int wave = (blockIdx.x * 256 + threadIdx.x) >> 6;
    int nw = gridDim.x * 4;
    const int NP = N_NODES / 2;

    int pair = wave;
    int2 oc = (pair < NP) ? noff[pair * 2 + h] : make_int2(0, 0);
    for (; pair < NP; pair += nw) {
        int pn = pair + nw;
        int2 ocn = (pn < NP) ? noff[pn * 2 + h] : make_int2(0, 0);   // prefetch
        int node = pair * 2 + h;
        int start = oc.x, c = oc.y;
        int end = start + c;
        float a[8] = {0, 0, 0, 0, 0, 0, 0, 0};
        for (int i = start; i < end; i += 16) {
            int i0 = i + g2, i1 = i + 4 + g2, i2 = i + 8 + g2, i3 = i + 12 + g2;
            unsigned p0 = csrp[(i0 < end) ? i0 : start];
            unsigned p1 = csrp[(i1 < end) ? i1 : start];
            unsigned p2 = csrp[(i2 < end) ? i2 : start];
            unsigned p3 = csrp[(i3 < end) ? i3 : start];
            float w0 = (i0 < end) ? (float)(p0 >> 17) * WSCALE : 0.f;
            float w1 = (i1 < end) ? (float)(p1 >> 17) * WSCALE : 0.f;
            float w2 = (i2 < end) ? (float)(p2 >> 17) * WSCALE : 0.f;
            float w3 = (i3 < end) ? (float)(p3 >> 17) * WSCALE : 0.f;
            uint4 q0 = fW4[((size_t)(p0 & 0x1ffffu) << 3) + s];
            uint4 q1 = fW4[((size_t)(p1 & 0x1ffffu) << 3) + s];
            uint4 q2 = fW4[((size_t)(p2 & 0x1ffffu) << 3) + s];
            uint4 q3 = fW4[((size_t)(p3 & 0x1ffffu) << 3) + s];
            a[0] = fmaf(bf_lo(q0.x), w0, a[0]); a[1] = fmaf(bf_hi(q0.x), w0, a[1]);
            a[2] = fmaf(bf_lo(q0.y), w0, a[2]); a[3] = fmaf(bf_hi(q0.y), w0, a[3]);
            a[4] = fmaf(bf_lo(q0.z), w0, a[4]); a[5] = fmaf(bf_hi(q0.z), w0, a[5]);
            a[6] = fmaf(bf_lo(q0.w), w0, a[6]); a[7] = fmaf(bf_hi(q0.w), w0, a[7]);
            a[0] = fmaf(bf_lo(q1.x), w1, a[0]); a[1] = fmaf(bf_hi(q1.x), w1, a[1]);
            a[2] = fmaf(bf_lo(q1.y), w1, a[2]); a[3] = fmaf(bf_hi(q1.y), w1, a[3]);
            a[4] = fmaf(bf_lo(q1.z), w1, a[4]); a[5] = fmaf(bf_hi(q1.z), w1, a[5]);
            a[6] = fmaf(bf_lo(q1.w), w1, a[6]); a[7] = fmaf(bf_hi(q1.w), w1, a[7]);
            a[0] = fmaf(bf_lo(q2.x), w2, a[0]); a[1] = fmaf(bf_hi(q2.x), w2, a[1]);
            a[2] = fmaf(bf_lo(q2.y), w2, a[2]); a[3] = fmaf(bf_hi(q2.y), w2, a[3]);
            a[4] = fmaf(bf_lo(q2.z), w2, a[4]); a[5] = fmaf(bf_hi(q2.z), w2, a[5]);
            a[6] = fmaf(bf_lo(q2.w), w2, a[6]); a[7] = fmaf(bf_hi(q2.w), w2, a[7]);
            a[0] = fmaf(bf_lo(q3.x), w3, a[0]); a[1] = fmaf(bf_hi(q3.x), w3, a[1]);
            a[2] = fmaf(bf_lo(q3.y), w3, a[2]); a[3] = fmaf(bf_hi(q3.y), w3, a[3]);
            a[4] = fmaf(bf_lo(q3.z), w3, a[4]); a[5] = fmaf(bf_hi(q3.z), w3, a[5]);
            a[6] = fmaf(bf_lo(q3.w), w3, a[6]); a[7] = fmaf(bf_hi(q3.w), w3, a[7]);
        }
        #pragma unroll
        for (int j = 0; j < 8; ++j) {     // reduce over the 4 groups of this half
            a[j] += __shfl_xor(a[j], 8, 64);
            a[j] += __shfl_xor(a[j], 16, 64);
        }
        float dinv = 1.0f / fmaxf((float)c, 1.0f);
        if (g2 == 0) {   // lanes 0..7 (half 0) and 32..39 (half 1)
            floatx4 o0, o1;
            o0.x = a[0] * dinv; o0.y = a[1] * dinv; o0.z = a[2] * dinv; o0.w = a[3] * dinv;
            o1.x = a[4] * dinv; o1.y = a[5] * dinv; o1.z = a[6] * dinv; o1.w = a[7] * dinv;
            floatx4* op = (floatx4*)out + (size_t)node * 16 + s * 2;
            __builtin_nontemporal_store(o0, op + 0);
            __builtin_nontemporal_store(o1, op + 1);
        }
        oc = ocn;
    }
}

extern "C" void kernel_launch(void* const* d_in, const int* in_sizes, int n_in,
                              void* d_out, int out_size, void* d_ws, size_t ws_size,
                              hipStream_t stream) {
    const float* feat = (const float*)d_in[0];
    const float* w    = (const float*)d_in[1];
    const float* W    = (const float*)d_in[2];
    const int*   src  = (const int*)d_in[3];
    const int*   dst  = (const int*)d_in[4];
    float* out = (float*)d_out;

    // fW 12.8 MB + binned 11.6 MB + csrp 5.8 MB + noff + cursor; ws is 256 MiB.
    unsigned short* fW = (unsigned short*)d_ws;                  // 16B-aligned
    uint2* binned  = (uint2*)(fW + (size_t)N_NODES * DIM);
    unsigned* csrp = (unsigned*)(binned + (size_t)NBINS * CAP);
    int2* noff     = (int2*)(csrp + (size_t)NBINS * CAP);
    int* cursor    = (int*)(noff + N_NODES);

    (void)hipMemsetAsync(cursor, 0, NBINS * sizeof(int), stream);

    k_fill_conv<<<NFB + CONVB, 256, 0, stream>>>(src, w, dst, cursor, binned,
                                                 feat, W, fW);
    k_sortbin<<<NBINS, 512, 0, stream>>>(binned, cursor, csrp, noff);
    k_gather<<<6144, 256, 0, stream>>>((const uint4*)fW, csrp, noff, out);
}